// Round 1
// baseline (354.684 us; speedup 1.0000x reference)
//
#include <hip/hip_runtime.h>
#include <hip/hip_bf16.h>
#include <stdint.h>

#define B_ 16
#define S_ 2048
#define D_ 512
#define TAU 0.1f
#define SCALE 0.04419417382415922f   // 1/sqrt(512)
#define BM 128
#define BN 32

typedef __attribute__((ext_vector_type(8))) __bf16 bf16x8;
typedef __attribute__((ext_vector_type(4))) float f32x4;
typedef __attribute__((ext_vector_type(8))) uint16_t u16x8;

__device__ __forceinline__ uint16_t f2bf(float f) {
  __hip_bfloat16 h = __float2bfloat16(f);
  return __builtin_bit_cast(uint16_t, h);
}

__device__ __forceinline__ void g2lds16(void* lds, const void* g) {
  __builtin_amdgcn_global_load_lds(
      (const __attribute__((address_space(1))) unsigned int*)g,
      (__attribute__((address_space(3))) unsigned int*)lds, 16, 0, 0);
}

// ---------------------------------------------------------------------------
// Convert fp32 x -> bf16 copies in ws:
//  xbf[b][t][d]  row-major, granule(16B) index XOR-swizzled by (t&7)  (for QK)
//  xt [b][d][t]  row-major in t, granule low-2-bits XOR-swizzled by (d&3) (for PV)
// ---------------------------------------------------------------------------
__global__ __launch_bounds__(256) void convert_kernel(
    const float* __restrict__ x, uint16_t* __restrict__ xbf,
    uint16_t* __restrict__ xt) {
  const int bid = blockIdx.x;
  const int b = bid >> 8;
  const int tt = (bid >> 3) & 31;
  const int dt = bid & 7;
  const int t0 = tt * 64, d0 = dt * 64;
  __shared__ uint16_t tile[64][72];   // 64 t rows x 64 d cols (+pad), 144B rows (16B-mult)
  const int tid = threadIdx.x;
  const float* xb = x + ((size_t)b * S_ + t0) * D_ + d0;

#pragma unroll
  for (int it = 0; it < 4; ++it) {
    int r = it * 16 + (tid >> 4);
    int c = (tid & 15) * 4;
    float4 v = *(const float4*)(xb + (size_t)r * D_ + c);
    tile[r][c + 0] = f2bf(v.x);
    tile[r][c + 1] = f2bf(v.y);
    tile[r][c + 2] = f2bf(v.z);
    tile[r][c + 3] = f2bf(v.w);
  }
  __syncthreads();

  // xbf rows: data granule gd stored at position gd ^ (t&7) (within 8-granule window)
#pragma unroll
  for (int it = 0; it < 2; ++it) {
    int G = it * 256 + tid;
    int tl = G >> 3, gl = G & 7;
    int t = t0 + tl;
    int p = (d0 >> 3) + (gl ^ (t & 7));
    u16x8 v = *(const u16x8*)&tile[tl][gl * 8];
    *(u16x8*)((char*)xbf + (size_t)(b * S_ + t) * 1024 + p * 16) = v;
  }
  // xt rows: data t-granule gl stored at (gl&~3) | ((gl ^ (d&3)) & 3)
#pragma unroll
  for (int it = 0; it < 2; ++it) {
    int G = it * 256 + tid;
    int dl = G >> 3, gl = G & 7;
    int d = d0 + dl;
    int p = (gl & ~3) | ((gl ^ (d & 3)) & 3);
    u16x8 v;
#pragma unroll
    for (int i = 0; i < 8; ++i) v[i] = tile[gl * 8 + i][dl];
    *(u16x8*)((char*)xt + (size_t)(b * D_ + d) * 4096 + t0 * 2 + p * 16) = v;
  }
}

// ---------------------------------------------------------------------------
// Fused attention: per block 128 queries x one batch; 8 waves x 16 q each.
// Pass A: rowsum of masked exp (max-free, scores bounded < ~30).
// Pass B: recompute scores, write normalized weights, fused PV via MFMA.
// ---------------------------------------------------------------------------
__global__ __launch_bounds__(512, 2) void attn_main(
    const uint16_t* __restrict__ xbf, const uint16_t* __restrict__ xtr,
    float* __restrict__ ctx, float* __restrict__ wout) {
  __shared__ uint16_t klds[BN * D_];    // 32 KB: swizzled image of 32 key rows
  __shared__ uint16_t xtlds[D_ * BN];   // 32 KB: [512 d][32 t] swizzled
  __shared__ uint16_t wlds[8][16][40];  // per-wave W tile (pad 40 to break banks)

  const int tid = threadIdx.x;
  const int wave = tid >> 6, lane = tid & 63;
  const int lg = lane >> 4, lr = lane & 15;
  const int bid = blockIdx.x;
  const int job = (bid & 7) * 32 + (bid >> 3);  // batch-contiguous per XCD
  const int b = job >> 4;
  const int q0 = (job & 15) * BM;

  const char* xb = (const char*)(xbf + (size_t)b * S_ * D_);
  const char* xtb = (const char*)(xtr + (size_t)b * D_ * S_);

  // Q fragments in registers: A[m=lr][k = 8*lg + i] per 32-d chunk c
  const int qrow = q0 + wave * 16 + lr;
  bf16x8 qf[16];
#pragma unroll
  for (int c = 0; c < 16; ++c) {
    int g = (4 * c + lg) ^ (qrow & 7);
    qf[c] = *(const bf16x8*)(xb + (size_t)qrow * 1024 + g * 16);
  }

  float psum[4] = {0.f, 0.f, 0.f, 0.f};

  // ---------------- pass A: row sums ----------------
  for (int kt = 0; kt < S_ / BN; ++kt) {
    const char* ksrc = xb + (size_t)kt * BN * 1024;
#pragma unroll
    for (int it = 0; it < 4; ++it) {
      int ob = it * 8192 + wave * 1024;
      g2lds16((char*)klds + ob, ksrc + ob + lane * 16);
    }
    __syncthreads();
    f32x4 acc0 = {0.f, 0.f, 0.f, 0.f}, acc1 = {0.f, 0.f, 0.f, 0.f};
#pragma unroll
    for (int c = 0; c < 16; ++c) {
      {
        int t = lr;
        int g = (4 * c + lg) ^ (t & 7);
        bf16x8 bf = *(const bf16x8*)((const char*)klds + t * 1024 + g * 16);
        acc0 = __builtin_amdgcn_mfma_f32_16x16x32_bf16(qf[c], bf, acc0, 0, 0, 0);
      }
      {
        int t = 16 + lr;
        int g = (4 * c + lg) ^ (t & 7);
        bf16x8 bf = *(const bf16x8*)((const char*)klds + t * 1024 + g * 16);
        acc1 = __builtin_amdgcn_mfma_f32_16x16x32_bf16(qf[c], bf, acc1, 0, 0, 0);
      }
    }
#pragma unroll
    for (int r = 0; r < 4; ++r) {
      float s0 = acc0[r] * SCALE;
      float s1 = acc1[r] * SCALE;
      psum[r] += (s0 > TAU ? __expf(s0) : 0.f) + (s1 > TAU ? __expf(s1) : 0.f);
    }
    __syncthreads();
  }

  // reduce across the 16 lanes of each group -> 1/rowsum
#pragma unroll
  for (int r = 0; r < 4; ++r) {
    float v = psum[r];
#pragma unroll
    for (int m = 1; m < 16; m <<= 1) v += __shfl_xor(v, m, 64);
    psum[r] = 1.f / v;
  }

  // ---------------- pass B: weights + PV ----------------
  f32x4 pv[32];
  const f32x4 fz = {0.f, 0.f, 0.f, 0.f};
#pragma unroll
  for (int n = 0; n < 32; ++n) pv[n] = fz;

  for (int kt = 0; kt < S_ / BN; ++kt) {
    const char* ksrc = xb + (size_t)kt * BN * 1024;
#pragma unroll
    for (int it = 0; it < 4; ++it) {
      int ob = it * 8192 + wave * 1024;
      g2lds16((char*)klds + ob, ksrc + ob + lane * 16);
    }
#pragma unroll
    for (int it = 0; it < 4; ++it) {
      int ob = it * 8192 + wave * 1024;
      int o = ob + lane * 16;
      const char* src = xtb + (size_t)(o >> 6) * 4096 + kt * 64 + (o & 63);
      g2lds16((char*)xtlds + ob, src);
    }
    __syncthreads();

    f32x4 acc0 = {0.f, 0.f, 0.f, 0.f}, acc1 = {0.f, 0.f, 0.f, 0.f};
#pragma unroll
    for (int c = 0; c < 16; ++c) {
      {
        int t = lr;
        int g = (4 * c + lg) ^ (t & 7);
        bf16x8 bf = *(const bf16x8*)((const char*)klds + t * 1024 + g * 16);
        acc0 = __builtin_amdgcn_mfma_f32_16x16x32_bf16(qf[c], bf, acc0, 0, 0, 0);
      }
      {
        int t = 16 + lr;
        int g = (4 * c + lg) ^ (t & 7);
        bf16x8 bf = *(const bf16x8*)((const char*)klds + t * 1024 + g * 16);
        acc1 = __builtin_amdgcn_mfma_f32_16x16x32_bf16(qf[c], bf, acc1, 0, 0, 0);
      }
    }

    // normalized weights -> global + per-wave LDS (bf16) for the PV A-operand
#pragma unroll
    for (int j = 0; j < 2; ++j) {
      f32x4 a = j ? acc1 : acc0;
#pragma unroll
      for (int r = 0; r < 4; ++r) {
        float s = a[r] * SCALE;
        float w = (s > TAU) ? __expf(s) * psum[r] : 0.f;
        int ql = wave * 16 + 4 * lg + r;
        wout[((size_t)(b * S_ + q0 + ql)) * S_ + kt * BN + j * 16 + lr] = w;
        wlds[wave][4 * lg + r][j * 16 + lr] = f2bf(w);
      }
    }

    // PV: A = W[16q x 32t] from wlds, B = XT rows (8 consecutive t at fixed d)
    bf16x8 wa = *(const bf16x8*)((const char*)&wlds[wave][0][0] + lr * 80 + lg * 16);
#pragma unroll
    for (int n = 0; n < 32; ++n) {
      int d = n * 16 + lr;
      int g = lg ^ (d & 3);
      bf16x8 bf = *(const bf16x8*)((const char*)xtlds + d * 64 + g * 16);
      pv[n] = __builtin_amdgcn_mfma_f32_16x16x32_bf16(wa, bf, pv[n], 0, 0, 0);
    }
    __syncthreads();
  }

  // epilogue: context
  const int qg = q0 + wave * 16 + 4 * lg;
#pragma unroll
  for (int n = 0; n < 32; ++n) {
#pragma unroll
    for (int r = 0; r < 4; ++r) {
      ctx[((size_t)(b * S_ + qg + r)) * D_ + n * 16 + lr] = pv[n][r];
    }
  }
}

// ---------------------------------------------------------------------------
// Fallback (only if ws_size < 64 MiB): naive fp32, correct but slow.
// ---------------------------------------------------------------------------
__global__ __launch_bounds__(256) void fb_weights(const float* __restrict__ x,
                                                  float* __restrict__ wout) {
  const int b = blockIdx.x >> 11;
  const int q = blockIdx.x & 2047;
  __shared__ float qv[512];
  __shared__ float red[256];
  const int tid = threadIdx.x;
  const float* xb = x + (size_t)b * S_ * D_;
  for (int d = tid; d < 512; d += 256) qv[d] = xb[(size_t)q * 512 + d];
  __syncthreads();
  float s[8];
  float lsum = 0.f;
#pragma unroll
  for (int i = 0; i < 8; ++i) {
    int k = i * 256 + tid;
    const float* xr = xb + (size_t)k * 512;
    float dot = 0.f;
    for (int d = 0; d < 512; ++d) dot += qv[d] * xr[d];
    dot *= SCALE;
    float e = (dot > TAU) ? __expf(dot) : 0.f;
    s[i] = e;
    lsum += e;
  }
  red[tid] = lsum;
  __syncthreads();
  for (int st = 128; st > 0; st >>= 1) {
    if (tid < st) red[tid] += red[tid + st];
    __syncthreads();
  }
  float inv = 1.f / red[0];
#pragma unroll
  for (int i = 0; i < 8; ++i)
    wout[((size_t)(b * S_ + q)) * S_ + i * 256 + tid] = s[i] * inv;
}

__global__ __launch_bounds__(256) void fb_ctx(const float* __restrict__ x,
                                              const float* __restrict__ wout,
                                              float* __restrict__ ctx) {
  const int b = blockIdx.x >> 11;
  const int q = blockIdx.x & 2047;
  const int tid = threadIdx.x;
  const float* xb = x + (size_t)b * S_ * D_;
  const float* wr = wout + ((size_t)(b * S_ + q)) * S_;
  float a0 = 0.f, a1 = 0.f;
  for (int k = 0; k < 2048; ++k) {
    float w = wr[k];
    a0 += w * xb[(size_t)k * 512 + tid];
    a1 += w * xb[(size_t)k * 512 + 256 + tid];
  }
  ctx[((size_t)(b * S_ + q)) * 512 + tid] = a0;
  ctx[((size_t)(b * S_ + q)) * 512 + 256 + tid] = a1;
}

// ---------------------------------------------------------------------------
extern "C" void kernel_launch(void* const* d_in, const int* in_sizes, int n_in,
                              void* d_out, int out_size, void* d_ws, size_t ws_size,
                              hipStream_t stream) {
  (void)in_sizes; (void)n_in; (void)out_size;
  const float* x = (const float*)d_in[0];
  float* ctx = (float*)d_out;
  float* wout = (float*)d_out + (size_t)B_ * S_ * D_;

  const size_t half = (size_t)B_ * S_ * D_ * 2;  // 32 MiB per bf16 copy
  if (ws_size >= 2 * half) {
    uint16_t* xbf = (uint16_t*)d_ws;
    uint16_t* xtr = (uint16_t*)((char*)d_ws + half);
    convert_kernel<<<dim3(4096), dim3(256), 0, stream>>>(x, xbf, xtr);
    attn_main<<<dim3(256), dim3(512), 0, stream>>>(xbf, xtr, ctx, wout);
  } else {
    fb_weights<<<dim3(32768), dim3(256), 0, stream>>>(x, wout);
    fb_ctx<<<dim3(32768), dim3(256), 0, stream>>>(x, wout, ctx);
  }
}